// Round 2
// baseline (364.057 us; speedup 1.0000x reference)
//
#include <hip/hip_runtime.h>
#include <math.h>

#define NQ 20
#define NL 4

// Quantum circuit sim, N=20 qubits, 4 layers, batch 16. State purely real -> f32.
// qubit q <-> bit (19-q). Per layer:
//   hpass: RY(0..4) + CNOT(0,1)..(3,4)    bits 19..15, 32 regs/thread
//   tpass: RY(5..19) + CNOT(4,5)..(18,19) bits 14..0, 2^15-chunk, 128KiB LDS,
//          3 register rounds of 5 bits, XOR swizzle phi(j)=j^((j>>5)&31)
//          (every LDS phase <=2-way conflicted == free)

__global__ void cs_kernel(const float* theta, float* cs) {
    int i = threadIdx.x;
    if (i < NL * NQ) {
        float s, c;
        sincosf(theta[i] * 0.5f, &s, &c);
        cs[2 * i]     = c;
        cs[2 * i + 1] = s;
    }
}

__global__ __launch_bounds__(256) void hpass_kernel(
    const float* in, float* out, const float* cs, int layer)
{
    int idx = blockIdx.x * 256 + threadIdx.x;    // 16 * 2^15 threads total
    int b   = idx >> 15;
    int low = idx & 32767;
    size_t base = ((size_t)b << 20) + (size_t)low;
    const float* src = in + base;
    const float2* cst = (const float2*)cs + layer * NQ;

    float v[32];
#pragma unroll
    for (int m = 0; m < 32; ++m) v[m] = src[(size_t)m << 15];

    // RY q=0..4: reg bit (4-q)
#pragma unroll
    for (int q = 0; q < 5; ++q) {
        float2 sc = cst[q];
        float c = sc.x, s = sc.y;
        int mask = 1 << (4 - q);
#pragma unroll
        for (int m = 0; m < 32; ++m) {
            if (!(m & mask)) {
                float a = v[m], bb = v[m | mask];
                v[m]        = c * a - s * bb;
                v[m | mask] = s * a + c * bb;
            }
        }
    }
    // CNOT(q,q+1) q=0..3: control reg bit (4-q), target reg bit (3-q)
#pragma unroll
    for (int q = 0; q < 4; ++q) {
        int cm = 1 << (4 - q), tm = 1 << (3 - q);
#pragma unroll
        for (int m = 0; m < 32; ++m) {
            if ((m & cm) && !(m & tm)) {
                float tmp = v[m]; v[m] = v[m | tm]; v[m | tm] = tmp;
            }
        }
    }

    float* dst = out + base;
#pragma unroll
    for (int m = 0; m < 32; ++m) dst[(size_t)m << 15] = v[m];
}

template <bool DO_ABS>
__global__ __launch_bounds__(1024) void tpass_kernel(
    float* st, const float* cs, int layer)
{
    __shared__ float lds[32768];                 // 128 KiB (gfx950: 160 KiB/CU)
    int t     = threadIdx.x;                     // 0..1023
    int blk   = blockIdx.x;                      // 0..511
    int b     = blk >> 5;
    int chunk = blk & 31;                        // global bits 19..15
    size_t base = ((size_t)b << 20) + ((size_t)chunk << 15);
    float* g = st + base;
    const float2* cst = (const float2*)cs + layer * NQ;

    float v[32];

    // ---- Round A: reg bits 14..10 (q5..9); j = m*1024 + t ----
#pragma unroll
    for (int m = 0; m < 32; ++m) v[m] = g[m * 1024 + t];

#pragma unroll
    for (int qq = 0; qq < 5; ++qq) {             // RY q = 5+qq, reg bit (4-qq)
        float2 sc = cst[5 + qq];
        float c = sc.x, s = sc.y;
        int mask = 1 << (4 - qq);
#pragma unroll
        for (int m = 0; m < 32; ++m) {
            if (!(m & mask)) {
                float a = v[m], bb = v[m | mask];
                v[m]        = c * a - s * bb;
                v[m | mask] = s * a + c * bb;
            }
        }
    }
    // CNOT(4,5): control bit 15 = chunk&1 (block-uniform), target reg bit 4
    if (chunk & 1) {
#pragma unroll
        for (int m = 0; m < 16; ++m) { float tmp = v[m]; v[m] = v[m | 16]; v[m | 16] = tmp; }
    }
    // CNOT(5,6)..(8,9): control reg bit (4-qq), target reg bit (3-qq)
#pragma unroll
    for (int qq = 0; qq < 4; ++qq) {
        int cm = 1 << (4 - qq), tm = 1 << (3 - qq);
#pragma unroll
        for (int m = 0; m < 32; ++m) {
            if ((m & cm) && !(m & tm)) {
                float tmp = v[m]; v[m] = v[m | tm]; v[m | tm] = tmp;
            }
        }
    }
    // A-write: phi(m*1024+t) = m*1024 + (t ^ (t>>5))  -> single base + imm offsets
    int ta = t ^ (t >> 5);
#pragma unroll
    for (int m = 0; m < 32; ++m) lds[m * 1024 + ta] = v[m];
    __syncthreads();

    // ---- Round B: reg bits 9..5 (q10..14); j = hi*1024 + k*32 + lo ----
    int hi = t >> 5, lo = t & 31;
#pragma unroll
    for (int k = 0; k < 32; ++k) v[k] = lds[hi * 1024 + k * 32 + (lo ^ k)];

#pragma unroll
    for (int qq = 0; qq < 5; ++qq) {             // RY q = 10+qq, reg bit (4-qq)
        float2 sc = cst[10 + qq];
        float c = sc.x, s = sc.y;
        int mask = 1 << (4 - qq);
#pragma unroll
        for (int k = 0; k < 32; ++k) {
            if (!(k & mask)) {
                float a = v[k], bb = v[k | mask];
                v[k]        = c * a - s * bb;
                v[k | mask] = s * a + c * bb;
            }
        }
    }
    // CNOT(9,10): control bit 10 = hi&1 (lane-varying -> cndmask), target reg bit 4
    if (hi & 1) {
#pragma unroll
        for (int k = 0; k < 16; ++k) { float tmp = v[k]; v[k] = v[k | 16]; v[k | 16] = tmp; }
    }
    // CNOT(10,11)..(13,14)
#pragma unroll
    for (int qq = 0; qq < 4; ++qq) {
        int cm = 1 << (4 - qq), tm = 1 << (3 - qq);
#pragma unroll
        for (int k = 0; k < 32; ++k) {
            if ((k & cm) && !(k & tm)) {
                float tmp = v[k]; v[k] = v[k | tm]; v[k | tm] = tmp;
            }
        }
    }
    // B-write: same thread-owned slots
#pragma unroll
    for (int k = 0; k < 32; ++k) lds[hi * 1024 + k * 32 + (lo ^ k)] = v[k];
    __syncthreads();

    // ---- Round C: reg bits 4..0 (q15..19); j = t*32 + k ----
    int tc = t & 31;
#pragma unroll
    for (int k = 0; k < 32; ++k) v[k] = lds[t * 32 + (k ^ tc)];

#pragma unroll
    for (int qq = 0; qq < 5; ++qq) {             // RY q = 15+qq, reg bit (4-qq)
        float2 sc = cst[15 + qq];
        float c = sc.x, s = sc.y;
        int mask = 1 << (4 - qq);
#pragma unroll
        for (int k = 0; k < 32; ++k) {
            if (!(k & mask)) {
                float a = v[k], bb = v[k | mask];
                v[k]        = c * a - s * bb;
                v[k | mask] = s * a + c * bb;
            }
        }
    }
    // CNOT(14,15): control bit 5 = t&1 (lane-varying), target reg bit 4
    if (t & 1) {
#pragma unroll
        for (int k = 0; k < 16; ++k) { float tmp = v[k]; v[k] = v[k | 16]; v[k | 16] = tmp; }
    }
    // CNOT(15,16)..(18,19)
#pragma unroll
    for (int qq = 0; qq < 4; ++qq) {
        int cm = 1 << (4 - qq), tm = 1 << (3 - qq);
#pragma unroll
        for (int k = 0; k < 32; ++k) {
            if ((k & cm) && !(k & tm)) {
                float tmp = v[k]; v[k] = v[k | tm]; v[k | tm] = tmp;
            }
        }
    }

    // store: thread owns 32 contiguous floats at g + t*32 -> 8x float4
    float4* dst = (float4*)(g + t * 32);
#pragma unroll
    for (int i = 0; i < 8; ++i) {
        float4 w;
        w.x = v[4 * i + 0]; w.y = v[4 * i + 1];
        w.z = v[4 * i + 2]; w.w = v[4 * i + 3];
        if (DO_ABS) {
            w.x = fabsf(w.x); w.y = fabsf(w.y);
            w.z = fabsf(w.z); w.w = fabsf(w.w);
        }
        dst[i] = w;
    }
}

extern "C" void kernel_launch(void* const* d_in, const int* in_sizes, int n_in,
                              void* d_out, int out_size, void* d_ws, size_t ws_size,
                              hipStream_t stream) {
    const float* x     = (const float*)d_in[0];   // (16, 2^20) f32
    const float* theta = (const float*)d_in[1];   // (80,) f32
    float* st = (float*)d_out;                    // state lives in d_out
    float* cs = (float*)d_ws;                     // 80 (cos,sin) pairs

    cs_kernel<<<1, 128, 0, stream>>>(theta, cs);

    for (int l = 0; l < 4; ++l) {
        hpass_kernel<<<2048, 256, 0, stream>>>(l == 0 ? x : st, st, cs, l);
        if (l < 3)
            tpass_kernel<false><<<512, 1024, 0, stream>>>(st, cs, l);
        else
            tpass_kernel<true><<<512, 1024, 0, stream>>>(st, cs, l);
    }
}